// Round 13
// baseline (221.729 us; speedup 1.0000x reference)
//
#include <hip/hip_runtime.h>
#include <hip/hip_bf16.h>

#define N_NODES   100000
#define N_EDGES   1250000
#define N_GRAPHS  512
#define HIDDEN    64
#define F_IN      3
#define N_CLASSES 5

// bucket sort parameters
#define BKT_SHIFT 9
#define BKT_NODES 512                                      // nodes per bucket
#define N_BKT     ((N_NODES + BKT_NODES - 1) / BKT_NODES)  // 196
#define CAP       8192                                     // fixed bucket capacity (mean 6400, +22 sigma)
#define EBLK      512                                      // edge blocks in k_scat
#define ECHUNK    ((N_EDGES + EBLK - 1) / EBLK)            // 2442
#define SCT       512                                      // k_scat threads

// bf16 helpers (RNE; inputs are finite)
__device__ __forceinline__ unsigned short f2bf(float f) {
    unsigned u = __float_as_uint(f);
    u += 0x7FFF + ((u >> 16) & 1);
    return (unsigned short)(u >> 16);
}

// ---------------------------------------------------------------------------
// k_scat: merged hist + bucket-base claim + scatter (+ head fold, gstart,
// gsum zero in extra blocks). Edges are cached in LDS during the hist pass,
// so src/dst are read from global exactly once.
__global__ void k_scat(const int* __restrict__ src, const int* __restrict__ dst,
                       const float* __restrict__ W2, const float* __restrict__ Wl,
                       const float* __restrict__ b2, const float* __restrict__ bl,
                       const int* __restrict__ batch,
                       int* __restrict__ gcur, int* __restrict__ ebuf,
                       float* __restrict__ Wc, float* __restrict__ bc,
                       int* __restrict__ gstart, float* __restrict__ gsum) {
    int b = blockIdx.x;
    int tid = threadIdx.x;
    if (b >= EBLK) {
        int bb = b - EBLK;
        if (bb == 0) {                      // head fold: Wc = W2@Wl, bc = b2@Wl+bl
            for (int t = tid; t < HIDDEN * N_CLASSES + N_CLASSES; t += SCT) {
                if (t < HIDDEN * N_CLASSES) {
                    int k = t / N_CLASSES, c = t % N_CLASSES;
                    float acc = 0.0f;
#pragma unroll
                    for (int j = 0; j < HIDDEN; j++)
                        acc = fmaf(W2[k * HIDDEN + j], Wl[j * N_CLASSES + c], acc);
                    Wc[t] = acc;
                } else {
                    int c = t - HIDDEN * N_CLASSES;
                    float acc = bl[c];
#pragma unroll
                    for (int j = 0; j < HIDDEN; j++)
                        acc = fmaf(b2[j], Wl[j * N_CLASSES + c], acc);
                    bc[c] = acc;
                }
            }
            return;
        }
        if (bb == 1) {                      // zero gsum (128 KB)
            for (int t = tid; t < N_GRAPHS * HIDDEN; t += SCT) gsum[t] = 0.0f;
            return;
        }
        int n = (bb - 2) * SCT + tid;       // gstart from sorted batch
        if (n >= N_NODES) return;
        if (n == 0) {
            for (int g = 0; g <= batch[0]; g++) gstart[g] = 0;
        } else {
            int b0 = batch[n - 1], b1 = batch[n];
            for (int g = b0 + 1; g <= b1; g++) gstart[g] = n;
        }
        if (n == N_NODES - 1) {
            for (int g = batch[n] + 1; g <= N_GRAPHS; g++) gstart[g] = N_NODES;
        }
        return;
    }
    // scatter blocks: edges cached in LDS across the two passes
    __shared__ int pk[ECHUNK];
    __shared__ unsigned char bkl[ECHUNK];
    __shared__ int h[N_BKT];
    __shared__ int cur[N_BKT];
    for (int i = tid; i < N_BKT; i += SCT) h[i] = 0;
    __syncthreads();
    int e0 = b * ECHUNK;
    int m = min(ECHUNK, N_EDGES - e0);
    for (int i = tid; i < m; i += SCT) {
        int s = src[e0 + i], d = dst[e0 + i];
        int bk = d >> BKT_SHIFT;
        pk[i] = (s << BKT_SHIFT) | (d & (BKT_NODES - 1));
        bkl[i] = (unsigned char)bk;
        atomicAdd(&h[bk], 1);
    }
    __syncthreads();
    for (int i = tid; i < N_BKT; i += SCT)
        cur[i] = atomicAdd(&gcur[i], h[i]);    // claim this block's run in bucket i
    __syncthreads();
    for (int i = tid; i < m; i += SCT) {
        int bk = bkl[i];
        int lp = atomicAdd(&cur[bk], 1);
        if (lp < CAP)                           // defensive (P~0 overflow)
            ebuf[bk * CAP + lp] = pk[i];
    }
}

// k_bktfill: per-bucket degree hist (LDS) -> rowptr/deg/dis/xs4 (coalesced),
// then LDS-cursor scatter of src into elist (contiguous CAP region per bucket).
// 1024 threads/block: 16 waves per bucket for latency hiding.
__global__ void k_bktfill(const int* __restrict__ ebuf, const int* __restrict__ gcur,
                          const float* __restrict__ x,
                          int* __restrict__ rowptr, int* __restrict__ deg,
                          float* __restrict__ dis, uint2* __restrict__ xs4,
                          int* __restrict__ elist) {
    __shared__ int cnt_l[BKT_NODES];
    __shared__ int cur_l[BKT_NODES];
    __shared__ int ps[BKT_NODES];
    int b = blockIdx.x, tid = threadIdx.x;   // 0..1023
    int n0 = b * BKT_NODES;
    int e0 = b * CAP;
    int cnt = min(gcur[b], CAP);
    int e1 = e0 + cnt;
    if (tid < BKT_NODES) cnt_l[tid] = 0;
    __syncthreads();
    for (int e = e0 + tid; e < e1; e += 1024)
        atomicAdd(&cnt_l[ebuf[e] & (BKT_NODES - 1)], 1);
    __syncthreads();
    if (tid < BKT_NODES) ps[tid] = cnt_l[tid];
    __syncthreads();
    for (int off = 1; off < BKT_NODES; off <<= 1) {
        int t = 0;
        if (tid < BKT_NODES && tid >= off) t = ps[tid - off];
        __syncthreads();
        if (tid < BKT_NODES) ps[tid] += t;
        __syncthreads();
    }
    if (tid < BKT_NODES) {
        int node = n0 + tid;
        int excl = ps[tid] - cnt_l[tid];       // exclusive scan
        cur_l[tid] = excl;
        if (node < N_NODES) {
            rowptr[node] = e0 + excl;
            deg[node] = cnt_l[tid];
            float dv = rsqrtf((float)cnt_l[tid] + 1.0f);
            dis[node] = dv;
            float x0 = x[node * 3 + 0], x1 = x[node * 3 + 1], x2 = x[node * 3 + 2];
            xs4[node] = make_uint2((unsigned)f2bf(x0 * dv) |
                                   ((unsigned)f2bf(x1 * dv) << 16),
                                   (unsigned)f2bf(x2 * dv));
        }
    }
    __syncthreads();
    for (int e = e0 + tid; e < e1; e += 1024) {
        int pe = ebuf[e];
        int pos = atomicAdd(&cur_l[pe & (BKT_NODES - 1)], 1);
        elist[e0 + pos] = ((unsigned)pe) >> BKT_SHIFT;
    }
}

// ---------------------------------------------------------------------------
// fused layer-1: wave per node. Lane-parallel 3-channel gather over edges
// (predicated, deg<=64 -> usually 1 step), butterfly-reduce, then
// h1 row = relu(aggx@W1 + b1)*dis quantized to uint8[64] + f32 row-scale.
__global__ void k_l1fused(const int* __restrict__ rp, const int* __restrict__ degA,
                          const int* __restrict__ elist,
                          const float* __restrict__ dis, const uint2* __restrict__ xs4,
                          const float* __restrict__ W1, const float* __restrict__ b1,
                          unsigned* __restrict__ h1q32, float* __restrict__ hscale) {
    int node = blockIdx.x * 4 + (threadIdx.x >> 6);
    int lane = threadIdx.x & 63;
    if (node >= N_NODES) return;
    int start = rp[node], dg = degA[node];
    float a0 = 0.f, a1 = 0.f, a2 = 0.f;
    for (int k = 0; k < dg; k += 64) {
        int idx = k + lane;
        bool act = idx < dg;
        int s = elist[start + (act ? idx : 0)];
        uint2 u = xs4[s];
        float msk = act ? 1.0f : 0.0f;
        a0 = fmaf(__uint_as_float(u.x << 16), msk, a0);
        a1 = fmaf(__uint_as_float(u.x & 0xFFFF0000u), msk, a1);
        a2 = fmaf(__uint_as_float(u.y << 16), msk, a2);
    }
#pragma unroll
    for (int off = 1; off < 64; off <<= 1) {
        a0 += __shfl_xor(a0, off);
        a1 += __shfl_xor(a1, off);
        a2 += __shfl_xor(a2, off);
    }
    uint2 un = xs4[node];
    float dn = dis[node];
    a0 = dn * (a0 + __uint_as_float(un.x << 16));
    a1 = dn * (a1 + __uint_as_float(un.x & 0xFFFF0000u));
    a2 = dn * (a2 + __uint_as_float(un.y << 16));
    float v = a0 * W1[lane] + a1 * W1[HIDDEN + lane] + a2 * W1[2 * HIDDEN + lane] + b1[lane];
    v = fmaxf(v, 0.0f) * dn;
    float m = v;
#pragma unroll
    for (int off = 1; off < 64; off <<= 1) m = fmaxf(m, __shfl_xor(m, off));
    float inv = (m > 0.0f) ? 255.0f / m : 0.0f;
    int q = (int)(v * inv + 0.5f);        // 0..255
    int base = lane & ~3;
    unsigned packed = (unsigned)__shfl(q, base) |
                      ((unsigned)__shfl(q, base + 1) << 8) |
                      ((unsigned)__shfl(q, base + 2) << 16) |
                      ((unsigned)__shfl(q, base + 3) << 24);
    unsigned mine = __shfl(packed, lane * 4);   // lanes 0..15 get dwords 0..15
    if (lane < 16) h1q32[node * 16 + lane] = mine;
    if (lane == 0) hscale[node] = m * (1.0f / 255.0f);
}

// ---------------------------------------------------------------------------
// fused 64-channel gather + mean-pool accumulate. Wave per node; 16 edges in
// flight (eg=lane>>2), uint4 full-row loads (16 rows = 1KB per instruction),
// predicated tail. Block's 4 waves stage rows in LDS, 64 threads merge
// same-graph rows -> ~1 atomicAdd-set per block.
__global__ void k_gatherpool(const int* __restrict__ rp, const int* __restrict__ degA,
                             const int* __restrict__ elist,
                             const float* __restrict__ dis,
                             const unsigned char* __restrict__ Hq,
                             const float* __restrict__ Hs,
                             const int* __restrict__ batch,
                             float* __restrict__ gsum) {
    __shared__ float acc_s[4][HIDDEN];
    __shared__ int gid[4];
    int w = threadIdx.x >> 6, lane = threadIdx.x & 63;
    int node = blockIdx.x * 4 + w;              // 25000*4 = 100000 exact
    int start = rp[node], dg = degA[node];
    int eg = lane >> 2;      // which of 16 concurrent edges
    int ch = lane & 3;       // which uint4 (16 channels) of the row
    float acc[16];
#pragma unroll
    for (int i = 0; i < 16; i++) acc[i] = 0.0f;
    for (int k = 0; k < dg; k += 16) {
        int idx = k + eg;
        bool act = idx < dg;
        int s = elist[start + (act ? idx : 0)];
        float sc = act ? Hs[s] : 0.0f;
        uint4 u = *(const uint4*)(Hq + ((size_t)s << 6) + (ch << 4));
#pragma unroll
        for (int i = 0; i < 4; i++)
            acc[i] = fmaf((float)((u.x >> (8 * i)) & 0xFF), sc, acc[i]);
#pragma unroll
        for (int i = 0; i < 4; i++)
            acc[4 + i] = fmaf((float)((u.y >> (8 * i)) & 0xFF), sc, acc[4 + i]);
#pragma unroll
        for (int i = 0; i < 4; i++)
            acc[8 + i] = fmaf((float)((u.z >> (8 * i)) & 0xFF), sc, acc[8 + i]);
#pragma unroll
        for (int i = 0; i < 4; i++)
            acc[12 + i] = fmaf((float)((u.w >> (8 * i)) & 0xFF), sc, acc[12 + i]);
    }
#pragma unroll
    for (int i = 0; i < 16; i++) {
        acc[i] += __shfl_xor(acc[i], 4);
        acc[i] += __shfl_xor(acc[i], 8);
        acc[i] += __shfl_xor(acc[i], 16);
        acc[i] += __shfl_xor(acc[i], 32);
    }
    if (lane == 0) gid[w] = batch[node];
    if (lane < 4) {                       // eg==0 lanes hold uint4 `lane`
        float dn = dis[node];
        float scN = Hs[node];
        uint4 u = *(const uint4*)(Hq + ((size_t)node << 6) + (lane << 4));
        float o[16];
#pragma unroll
        for (int i = 0; i < 4; i++)
            o[i] = dn * fmaf((float)((u.x >> (8 * i)) & 0xFF), scN, acc[i]);
#pragma unroll
        for (int i = 0; i < 4; i++)
            o[4 + i] = dn * fmaf((float)((u.y >> (8 * i)) & 0xFF), scN, acc[4 + i]);
#pragma unroll
        for (int i = 0; i < 4; i++)
            o[8 + i] = dn * fmaf((float)((u.z >> (8 * i)) & 0xFF), scN, acc[8 + i]);
#pragma unroll
        for (int i = 0; i < 4; i++)
            o[12 + i] = dn * fmaf((float)((u.w >> (8 * i)) & 0xFF), scN, acc[12 + i]);
        float* dst = &acc_s[w][lane * 16];
        *(float4*)(dst + 0)  = make_float4(o[0], o[1], o[2], o[3]);
        *(float4*)(dst + 4)  = make_float4(o[4], o[5], o[6], o[7]);
        *(float4*)(dst + 8)  = make_float4(o[8], o[9], o[10], o[11]);
        *(float4*)(dst + 12) = make_float4(o[12], o[13], o[14], o[15]);
    }
    __syncthreads();
    if (threadIdx.x < HIDDEN) {
        int t = threadIdx.x;
#pragma unroll
        for (int wv = 0; wv < 4; wv++) {
            int gw = gid[wv];
            bool first = true;
#pragma unroll
            for (int u = 0; u < wv; u++)
                if (gid[u] == gw) first = false;
            if (first) {
                float s = acc_s[wv][t];
#pragma unroll
                for (int u2 = wv + 1; u2 < 4; u2++)
                    if (gid[u2] == gw) s += acc_s[u2][t];
                atomicAdd(&gsum[gw * HIDDEN + t], s);
            }
        }
    }
}

// head: out[g,c] = (gsum[g,:] @ Wc[:,c]) / max(cnt,1) + bc[c]
__global__ void k_head(const float* __restrict__ gsum, const int* __restrict__ gstart,
                       const float* __restrict__ Wc, const float* __restrict__ bc,
                       float* __restrict__ out) {
    int t = blockIdx.x * blockDim.x + threadIdx.x;   // g*5 + c
    if (t >= N_GRAPHS * N_CLASSES) return;
    int g = t / N_CLASSES, c = t % N_CLASSES;
    float cntf = fmaxf((float)(gstart[g + 1] - gstart[g]), 1.0f);
    float dot = 0.0f;
#pragma unroll
    for (int k = 0; k < HIDDEN; k++)
        dot = fmaf(gsum[g * HIDDEN + k], Wc[k * N_CLASSES + c], dot);
    out[t] = dot / cntf + bc[c];
}

// ---------------------------------------------------------------------------
extern "C" void kernel_launch(void* const* d_in, const int* in_sizes, int n_in,
                              void* d_out, int out_size, void* d_ws, size_t ws_size,
                              hipStream_t stream) {
    const float* x     = (const float*)d_in[0];
    const int*   ei    = (const int*)  d_in[1];   // [2, N_EDGES] flat: src then dst
    const int*   batch = (const int*)  d_in[2];
    const float* W1    = (const float*)d_in[3];
    const float* b1    = (const float*)d_in[4];
    const float* W2    = (const float*)d_in[5];
    const float* b2    = (const float*)d_in[6];
    const float* Wl    = (const float*)d_in[7];
    const float* bl    = (const float*)d_in[8];
    float* out = (float*)d_out;

    const int* src = ei;
    const int* dst = ei + N_EDGES;

    // workspace layout (4B words; word-offset parity keeps xs4/h1q 8B-aligned,
    // h1q 16B-aligned for uint4 loads)
    int*   gcur    = (int*)d_ws;                         // 196, pad to 256
    int*   ebuf    = gcur + 256;                         // N_BKT*CAP (padded buckets)
    int*   elist   = ebuf + N_BKT * CAP;                 // N_BKT*CAP
    int*   rp      = elist + N_BKT * CAP;                // N
    int*   deg     = rp + N_NODES;                       // N
    float* dis     = (float*)(deg + N_NODES);            // N
    float* hscale  = dis + N_NODES;                      // N
    uint2* xs4     = (uint2*)(hscale + N_NODES);         // N uint2 (8B-aligned)
    unsigned* h1q32 = (unsigned*)(xs4 + N_NODES);        // 16N words (uint8 rows, 16B-aligned)
    float* gsum    = (float*)(h1q32 + (size_t)N_NODES * 16);  // 512*64
    int*   gstart  = (int*)(gsum + N_GRAPHS * HIDDEN);   // N_GRAPHS+1 (pad 516)
    float* Wc      = (float*)(gstart + 516);             // 64*5
    float* bc      = Wc + HIDDEN * N_CLASSES;            // 5

    const int BS = 256;
    const int g_nodes_sct = (N_NODES + SCT - 1) / SCT;   // 196 gstart blocks
    const int g_wave4 = (N_NODES + 3) / 4;               // wave-per-node kernels

    // merged CSR scatter + head fold + gstart + gsum zero
    hipMemsetAsync(gcur, 0, N_BKT * sizeof(int), stream);
    k_scat<<<EBLK + 2 + g_nodes_sct, SCT, 0, stream>>>(src, dst, W2, Wl, b2, bl, batch,
                                                       gcur, ebuf, Wc, bc, gstart, gsum);
    k_bktfill<<<N_BKT, 1024, 0, stream>>>(ebuf, gcur, x, rp, deg, dis, xs4, elist);

    // fused layer 1 (lane-parallel 3ch gather + W1 + quantize to uint8 rows)
    k_l1fused<<<g_wave4, BS, 0, stream>>>(rp, deg, elist, dis, xs4, W1, b1,
                                          h1q32, hscale);

    // layer 2 aggregation fused with mean-pool accumulation (wave per node)
    k_gatherpool<<<N_NODES / 4, BS, 0, stream>>>(rp, deg, elist, dis,
                                                 (const unsigned char*)h1q32,
                                                 hscale, batch, gsum);

    // folded head
    k_head<<<(N_GRAPHS * N_CLASSES + BS - 1) / BS, BS, 0, stream>>>(gsum, gstart, Wc, bc, out);
}

// Round 14
// 197.390 us; speedup vs baseline: 1.1233x; 1.1233x over previous
//
#include <hip/hip_runtime.h>
#include <hip/hip_bf16.h>

#define N_NODES   100000
#define N_EDGES   1250000
#define N_GRAPHS  512
#define HIDDEN    64
#define F_IN      3
#define N_CLASSES 5

// bucket sort parameters
#define BKT_SHIFT 9
#define BKT_NODES 512                                      // nodes per bucket
#define N_BKT     ((N_NODES + BKT_NODES - 1) / BKT_NODES)  // 196
#define CAP       8192                                     // fixed bucket capacity (mean 6400, +22 sigma)
#define EBLK      512                                      // edge blocks in k_scat
#define ECHUNK    ((N_EDGES + EBLK - 1) / EBLK)            // 2442
#define SCT       512                                      // k_scat threads

// bf16 helpers (RNE; inputs are finite)
__device__ __forceinline__ unsigned short f2bf(float f) {
    unsigned u = __float_as_uint(f);
    u += 0x7FFF + ((u >> 16) & 1);
    return (unsigned short)(u >> 16);
}

// ---------------------------------------------------------------------------
// k_scat: merged hist + bucket-base claim + scatter (+ head fold, gstart,
// gsum zero in extra blocks). Edges are cached in LDS during the hist pass,
// so src/dst are read from global exactly once.  [kept from R13: ~9us win]
__global__ void k_scat(const int* __restrict__ src, const int* __restrict__ dst,
                       const float* __restrict__ W2, const float* __restrict__ Wl,
                       const float* __restrict__ b2, const float* __restrict__ bl,
                       const int* __restrict__ batch,
                       int* __restrict__ gcur, int* __restrict__ ebuf,
                       float* __restrict__ Wc, float* __restrict__ bc,
                       int* __restrict__ gstart, float* __restrict__ gsum) {
    int b = blockIdx.x;
    int tid = threadIdx.x;
    if (b >= EBLK) {
        int bb = b - EBLK;
        if (bb == 0) {                      // head fold: Wc = W2@Wl, bc = b2@Wl+bl
            for (int t = tid; t < HIDDEN * N_CLASSES + N_CLASSES; t += SCT) {
                if (t < HIDDEN * N_CLASSES) {
                    int k = t / N_CLASSES, c = t % N_CLASSES;
                    float acc = 0.0f;
#pragma unroll
                    for (int j = 0; j < HIDDEN; j++)
                        acc = fmaf(W2[k * HIDDEN + j], Wl[j * N_CLASSES + c], acc);
                    Wc[t] = acc;
                } else {
                    int c = t - HIDDEN * N_CLASSES;
                    float acc = bl[c];
#pragma unroll
                    for (int j = 0; j < HIDDEN; j++)
                        acc = fmaf(b2[j], Wl[j * N_CLASSES + c], acc);
                    bc[c] = acc;
                }
            }
            return;
        }
        if (bb == 1) {                      // zero gsum (128 KB)
            for (int t = tid; t < N_GRAPHS * HIDDEN; t += SCT) gsum[t] = 0.0f;
            return;
        }
        int n = (bb - 2) * SCT + tid;       // gstart from sorted batch
        if (n >= N_NODES) return;
        if (n == 0) {
            for (int g = 0; g <= batch[0]; g++) gstart[g] = 0;
        } else {
            int b0 = batch[n - 1], b1 = batch[n];
            for (int g = b0 + 1; g <= b1; g++) gstart[g] = n;
        }
        if (n == N_NODES - 1) {
            for (int g = batch[n] + 1; g <= N_GRAPHS; g++) gstart[g] = N_NODES;
        }
        return;
    }
    // scatter blocks: edges cached in LDS across the two passes
    __shared__ int pk[ECHUNK];
    __shared__ unsigned char bkl[ECHUNK];
    __shared__ int h[N_BKT];
    __shared__ int cur[N_BKT];
    for (int i = tid; i < N_BKT; i += SCT) h[i] = 0;
    __syncthreads();
    int e0 = b * ECHUNK;
    int m = min(ECHUNK, N_EDGES - e0);
    for (int i = tid; i < m; i += SCT) {
        int s = src[e0 + i], d = dst[e0 + i];
        int bk = d >> BKT_SHIFT;
        pk[i] = (s << BKT_SHIFT) | (d & (BKT_NODES - 1));
        bkl[i] = (unsigned char)bk;
        atomicAdd(&h[bk], 1);
    }
    __syncthreads();
    for (int i = tid; i < N_BKT; i += SCT)
        cur[i] = atomicAdd(&gcur[i], h[i]);    // claim this block's run in bucket i
    __syncthreads();
    for (int i = tid; i < m; i += SCT) {
        int bk = bkl[i];
        int lp = atomicAdd(&cur[bk], 1);
        if (lp < CAP)                           // defensive (P~0 overflow)
            ebuf[bk * CAP + lp] = pk[i];
    }
}

// k_bktfill: per-bucket degree hist (LDS) -> rowptr/deg/dis/xs4 (coalesced),
// then LDS-cursor scatter of src into elist (contiguous CAP region per bucket).
// 1024 threads/block: 16 waves per bucket for latency hiding.
__global__ void k_bktfill(const int* __restrict__ ebuf, const int* __restrict__ gcur,
                          const float* __restrict__ x,
                          int* __restrict__ rowptr, int* __restrict__ deg,
                          float* __restrict__ dis, uint2* __restrict__ xs4,
                          int* __restrict__ elist) {
    __shared__ int cnt_l[BKT_NODES];
    __shared__ int cur_l[BKT_NODES];
    __shared__ int ps[BKT_NODES];
    int b = blockIdx.x, tid = threadIdx.x;   // 0..1023
    int n0 = b * BKT_NODES;
    int e0 = b * CAP;
    int cnt = min(gcur[b], CAP);
    int e1 = e0 + cnt;
    if (tid < BKT_NODES) cnt_l[tid] = 0;
    __syncthreads();
    for (int e = e0 + tid; e < e1; e += 1024)
        atomicAdd(&cnt_l[ebuf[e] & (BKT_NODES - 1)], 1);
    __syncthreads();
    if (tid < BKT_NODES) ps[tid] = cnt_l[tid];
    __syncthreads();
    for (int off = 1; off < BKT_NODES; off <<= 1) {
        int t = 0;
        if (tid < BKT_NODES && tid >= off) t = ps[tid - off];
        __syncthreads();
        if (tid < BKT_NODES) ps[tid] += t;
        __syncthreads();
    }
    if (tid < BKT_NODES) {
        int node = n0 + tid;
        int excl = ps[tid] - cnt_l[tid];       // exclusive scan
        cur_l[tid] = excl;
        if (node < N_NODES) {
            rowptr[node] = e0 + excl;
            deg[node] = cnt_l[tid];
            float dv = rsqrtf((float)cnt_l[tid] + 1.0f);
            dis[node] = dv;
            float x0 = x[node * 3 + 0], x1 = x[node * 3 + 1], x2 = x[node * 3 + 2];
            xs4[node] = make_uint2((unsigned)f2bf(x0 * dv) |
                                   ((unsigned)f2bf(x1 * dv) << 16),
                                   (unsigned)f2bf(x2 * dv));
        }
    }
    __syncthreads();
    for (int e = e0 + tid; e < e1; e += 1024) {
        int pe = ebuf[e];
        int pos = atomicAdd(&cur_l[pe & (BKT_NODES - 1)], 1);
        elist[e0 + pos] = ((unsigned)pe) >> BKT_SHIFT;
    }
}

// ---------------------------------------------------------------------------
// fused layer-1: wave per node. Lane-parallel 3-channel gather over edges
// (predicated, deg<=64 -> usually 1 step), butterfly-reduce, then
// h1 row = relu(aggx@W1 + b1)*dis quantized to uint8[64] + f32 row-scale.
__global__ void k_l1fused(const int* __restrict__ rp, const int* __restrict__ degA,
                          const int* __restrict__ elist,
                          const float* __restrict__ dis, const uint2* __restrict__ xs4,
                          const float* __restrict__ W1, const float* __restrict__ b1,
                          unsigned* __restrict__ h1q32, float* __restrict__ hscale) {
    int node = blockIdx.x * 4 + (threadIdx.x >> 6);
    int lane = threadIdx.x & 63;
    if (node >= N_NODES) return;
    int start = rp[node], dg = degA[node];
    float a0 = 0.f, a1 = 0.f, a2 = 0.f;
    for (int k = 0; k < dg; k += 64) {
        int idx = k + lane;
        bool act = idx < dg;
        int s = elist[start + (act ? idx : 0)];
        uint2 u = xs4[s];
        float msk = act ? 1.0f : 0.0f;
        a0 = fmaf(__uint_as_float(u.x << 16), msk, a0);
        a1 = fmaf(__uint_as_float(u.x & 0xFFFF0000u), msk, a1);
        a2 = fmaf(__uint_as_float(u.y << 16), msk, a2);
    }
#pragma unroll
    for (int off = 1; off < 64; off <<= 1) {
        a0 += __shfl_xor(a0, off);
        a1 += __shfl_xor(a1, off);
        a2 += __shfl_xor(a2, off);
    }
    uint2 un = xs4[node];
    float dn = dis[node];
    a0 = dn * (a0 + __uint_as_float(un.x << 16));
    a1 = dn * (a1 + __uint_as_float(un.x & 0xFFFF0000u));
    a2 = dn * (a2 + __uint_as_float(un.y << 16));
    float v = a0 * W1[lane] + a1 * W1[HIDDEN + lane] + a2 * W1[2 * HIDDEN + lane] + b1[lane];
    v = fmaxf(v, 0.0f) * dn;
    float m = v;
#pragma unroll
    for (int off = 1; off < 64; off <<= 1) m = fmaxf(m, __shfl_xor(m, off));
    float inv = (m > 0.0f) ? 255.0f / m : 0.0f;
    int q = (int)(v * inv + 0.5f);        // 0..255
    int base = lane & ~3;
    unsigned packed = (unsigned)__shfl(q, base) |
                      ((unsigned)__shfl(q, base + 1) << 8) |
                      ((unsigned)__shfl(q, base + 2) << 16) |
                      ((unsigned)__shfl(q, base + 3) << 24);
    unsigned mine = __shfl(packed, lane * 4);   // lanes 0..15 get dwords 0..15
    if (lane < 16) h1q32[node * 16 + lane] = mine;
    if (lane == 0) hscale[node] = m * (1.0f / 255.0f);
}

// ---------------------------------------------------------------------------
// fused 64-channel gather + mean-pool accumulate. Wave per node; 8 edges in
// flight (eg=lane>>3), uint2 row loads, predicated tail.  [reverted to the
// measured-best R11 inner loop; R13's 16-wide uint4 variant regressed 55->85us]
// Block's 4 waves stage rows in LDS, 64 threads merge same-graph rows ->
// ~1 atomicAdd-set per block.
__global__ void k_gatherpool(const int* __restrict__ rp, const int* __restrict__ degA,
                             const int* __restrict__ elist,
                             const float* __restrict__ dis,
                             const unsigned char* __restrict__ Hq,
                             const float* __restrict__ Hs,
                             const int* __restrict__ batch,
                             float* __restrict__ gsum) {
    __shared__ float acc_s[4][HIDDEN];
    __shared__ int gid[4];
    int w = threadIdx.x >> 6, lane = threadIdx.x & 63;
    int node = blockIdx.x * 4 + w;              // 25000*4 = 100000 exact
    int start = rp[node], dg = degA[node];
    int eg = lane >> 3;      // which of 8 concurrent edges
    int ch = lane & 7;       // which byte-octet (uint2) of the row
    float acc[8] = {0.f, 0.f, 0.f, 0.f, 0.f, 0.f, 0.f, 0.f};
    for (int k = 0; k < dg; k += 8) {
        int idx = k + eg;
        bool act = idx < dg;
        int s = elist[start + (act ? idx : 0)];
        float sc = act ? Hs[s] : 0.0f;
        uint2 u = *(const uint2*)(Hq + ((size_t)s << 6) + (ch << 3));
#pragma unroll
        for (int i = 0; i < 4; i++)
            acc[i] = fmaf((float)((u.x >> (8 * i)) & 0xFF), sc, acc[i]);
#pragma unroll
        for (int i = 0; i < 4; i++)
            acc[4 + i] = fmaf((float)((u.y >> (8 * i)) & 0xFF), sc, acc[4 + i]);
    }
#pragma unroll
    for (int i = 0; i < 8; i++) {
        acc[i] += __shfl_xor(acc[i], 8);
        acc[i] += __shfl_xor(acc[i], 16);
        acc[i] += __shfl_xor(acc[i], 32);
    }
    if (lane == 0) gid[w] = batch[node];
    if (lane < 8) {                       // eg==0 lanes hold octet `lane`
        float dn = dis[node];
        float scN = Hs[node];
        uint2 u = *(const uint2*)(Hq + ((size_t)node << 6) + (lane << 3));
        float o[8];
#pragma unroll
        for (int i = 0; i < 4; i++)
            o[i] = dn * fmaf((float)((u.x >> (8 * i)) & 0xFF), scN, acc[i]);
#pragma unroll
        for (int i = 0; i < 4; i++)
            o[4 + i] = dn * fmaf((float)((u.y >> (8 * i)) & 0xFF), scN, acc[4 + i]);
        *(float4*)&acc_s[w][lane * 8]     = make_float4(o[0], o[1], o[2], o[3]);
        *(float4*)&acc_s[w][lane * 8 + 4] = make_float4(o[4], o[5], o[6], o[7]);
    }
    __syncthreads();
    if (threadIdx.x < HIDDEN) {
        int t = threadIdx.x;
#pragma unroll
        for (int wv = 0; wv < 4; wv++) {
            int gw = gid[wv];
            bool first = true;
#pragma unroll
            for (int u = 0; u < wv; u++)
                if (gid[u] == gw) first = false;
            if (first) {
                float s = acc_s[wv][t];
#pragma unroll
                for (int u2 = wv + 1; u2 < 4; u2++)
                    if (gid[u2] == gw) s += acc_s[u2][t];
                atomicAdd(&gsum[gw * HIDDEN + t], s);
            }
        }
    }
}

// head: out[g,c] = (gsum[g,:] @ Wc[:,c]) / max(cnt,1) + bc[c]
__global__ void k_head(const float* __restrict__ gsum, const int* __restrict__ gstart,
                       const float* __restrict__ Wc, const float* __restrict__ bc,
                       float* __restrict__ out) {
    int t = blockIdx.x * blockDim.x + threadIdx.x;   // g*5 + c
    if (t >= N_GRAPHS * N_CLASSES) return;
    int g = t / N_CLASSES, c = t % N_CLASSES;
    float cntf = fmaxf((float)(gstart[g + 1] - gstart[g]), 1.0f);
    float dot = 0.0f;
#pragma unroll
    for (int k = 0; k < HIDDEN; k++)
        dot = fmaf(gsum[g * HIDDEN + k], Wc[k * N_CLASSES + c], dot);
    out[t] = dot / cntf + bc[c];
}

// ---------------------------------------------------------------------------
extern "C" void kernel_launch(void* const* d_in, const int* in_sizes, int n_in,
                              void* d_out, int out_size, void* d_ws, size_t ws_size,
                              hipStream_t stream) {
    const float* x     = (const float*)d_in[0];
    const int*   ei    = (const int*)  d_in[1];   // [2, N_EDGES] flat: src then dst
    const int*   batch = (const int*)  d_in[2];
    const float* W1    = (const float*)d_in[3];
    const float* b1    = (const float*)d_in[4];
    const float* W2    = (const float*)d_in[5];
    const float* b2    = (const float*)d_in[6];
    const float* Wl    = (const float*)d_in[7];
    const float* bl    = (const float*)d_in[8];
    float* out = (float*)d_out;

    const int* src = ei;
    const int* dst = ei + N_EDGES;

    // workspace layout (4B words; word-offset parity keeps xs4/h1q 8B-aligned)
    int*   gcur    = (int*)d_ws;                         // 196, pad to 256
    int*   ebuf    = gcur + 256;                         // N_BKT*CAP (padded buckets)
    int*   elist   = ebuf + N_BKT * CAP;                 // N_BKT*CAP
    int*   rp      = elist + N_BKT * CAP;                // N
    int*   deg     = rp + N_NODES;                       // N
    float* dis     = (float*)(deg + N_NODES);            // N
    float* hscale  = dis + N_NODES;                      // N
    uint2* xs4     = (uint2*)(hscale + N_NODES);         // N uint2 (8B-aligned)
    unsigned* h1q32 = (unsigned*)(xs4 + N_NODES);        // 16N words (uint8 rows)
    float* gsum    = (float*)(h1q32 + (size_t)N_NODES * 16);  // 512*64
    int*   gstart  = (int*)(gsum + N_GRAPHS * HIDDEN);   // N_GRAPHS+1 (pad 516)
    float* Wc      = (float*)(gstart + 516);             // 64*5
    float* bc      = Wc + HIDDEN * N_CLASSES;            // 5

    const int BS = 256;
    const int g_nodes_sct = (N_NODES + SCT - 1) / SCT;   // 196 gstart blocks
    const int g_wave4 = (N_NODES + 3) / 4;               // wave-per-node kernels

    // merged CSR scatter + head fold + gstart + gsum zero
    hipMemsetAsync(gcur, 0, N_BKT * sizeof(int), stream);
    k_scat<<<EBLK + 2 + g_nodes_sct, SCT, 0, stream>>>(src, dst, W2, Wl, b2, bl, batch,
                                                       gcur, ebuf, Wc, bc, gstart, gsum);
    k_bktfill<<<N_BKT, 1024, 0, stream>>>(ebuf, gcur, x, rp, deg, dis, xs4, elist);

    // fused layer 1 (lane-parallel 3ch gather + W1 + quantize to uint8 rows)
    k_l1fused<<<g_wave4, BS, 0, stream>>>(rp, deg, elist, dis, xs4, W1, b1,
                                          h1q32, hscale);

    // layer 2 aggregation fused with mean-pool accumulation (wave per node)
    k_gatherpool<<<N_NODES / 4, BS, 0, stream>>>(rp, deg, elist, dis,
                                                 (const unsigned char*)h1q32,
                                                 hscale, batch, gsum);

    // folded head
    k_head<<<(N_GRAPHS * N_CLASSES + BS - 1) / BS, BS, 0, stream>>>(gsum, gstart, Wc, bc, out);
}

// Round 15
// 193.893 us; speedup vs baseline: 1.1436x; 1.0180x over previous
//
#include <hip/hip_runtime.h>
#include <hip/hip_bf16.h>

#define N_NODES   100000
#define N_EDGES   1250000
#define N_GRAPHS  512
#define HIDDEN    64
#define F_IN      3
#define N_CLASSES 5

// bucket sort parameters
#define BKT_SHIFT 9
#define BKT_NODES 512                                      // nodes per bucket
#define N_BKT     ((N_NODES + BKT_NODES - 1) / BKT_NODES)  // 196
#define CAP       8192                                     // fixed bucket capacity (mean 6400, +22 sigma)
#define EBLK      512                                      // edge blocks in k_scat
#define ECHUNK    ((N_EDGES + EBLK - 1) / EBLK)            // 2442
#define SCT       512                                      // k_scat threads
#define NREP      8                                        // gsum replicas (spread atomic contention)

// bf16 helpers (RNE; inputs are finite)
__device__ __forceinline__ unsigned short f2bf(float f) {
    unsigned u = __float_as_uint(f);
    u += 0x7FFF + ((u >> 16) & 1);
    return (unsigned short)(u >> 16);
}

// ---------------------------------------------------------------------------
// k_scat: merged hist + bucket-base claim + scatter (+ head fold, gstart in
// extra blocks). Edges are cached in LDS during the hist pass, so src/dst are
// read from global exactly once.
__global__ void k_scat(const int* __restrict__ src, const int* __restrict__ dst,
                       const float* __restrict__ W2, const float* __restrict__ Wl,
                       const float* __restrict__ b2, const float* __restrict__ bl,
                       const int* __restrict__ batch,
                       int* __restrict__ gcur, int* __restrict__ ebuf,
                       float* __restrict__ Wc, float* __restrict__ bc,
                       int* __restrict__ gstart) {
    int b = blockIdx.x;
    int tid = threadIdx.x;
    if (b >= EBLK) {
        int bb = b - EBLK;
        if (bb == 0) {                      // head fold: Wc = W2@Wl, bc = b2@Wl+bl
            for (int t = tid; t < HIDDEN * N_CLASSES + N_CLASSES; t += SCT) {
                if (t < HIDDEN * N_CLASSES) {
                    int k = t / N_CLASSES, c = t % N_CLASSES;
                    float acc = 0.0f;
#pragma unroll
                    for (int j = 0; j < HIDDEN; j++)
                        acc = fmaf(W2[k * HIDDEN + j], Wl[j * N_CLASSES + c], acc);
                    Wc[t] = acc;
                } else {
                    int c = t - HIDDEN * N_CLASSES;
                    float acc = bl[c];
#pragma unroll
                    for (int j = 0; j < HIDDEN; j++)
                        acc = fmaf(b2[j], Wl[j * N_CLASSES + c], acc);
                    bc[c] = acc;
                }
            }
            return;
        }
        int n = (bb - 1) * SCT + tid;       // gstart from sorted batch
        if (n >= N_NODES) return;
        if (n == 0) {
            for (int g = 0; g <= batch[0]; g++) gstart[g] = 0;
        } else {
            int b0 = batch[n - 1], b1 = batch[n];
            for (int g = b0 + 1; g <= b1; g++) gstart[g] = n;
        }
        if (n == N_NODES - 1) {
            for (int g = batch[n] + 1; g <= N_GRAPHS; g++) gstart[g] = N_NODES;
        }
        return;
    }
    // scatter blocks: edges cached in LDS across the two passes
    __shared__ int pk[ECHUNK];
    __shared__ unsigned char bkl[ECHUNK];
    __shared__ int h[N_BKT];
    __shared__ int cur[N_BKT];
    for (int i = tid; i < N_BKT; i += SCT) h[i] = 0;
    __syncthreads();
    int e0 = b * ECHUNK;
    int m = min(ECHUNK, N_EDGES - e0);
    for (int i = tid; i < m; i += SCT) {
        int s = src[e0 + i], d = dst[e0 + i];
        int bk = d >> BKT_SHIFT;
        pk[i] = (s << BKT_SHIFT) | (d & (BKT_NODES - 1));
        bkl[i] = (unsigned char)bk;
        atomicAdd(&h[bk], 1);
    }
    __syncthreads();
    for (int i = tid; i < N_BKT; i += SCT)
        cur[i] = atomicAdd(&gcur[i], h[i]);    // claim this block's run in bucket i
    __syncthreads();
    for (int i = tid; i < m; i += SCT) {
        int bk = bkl[i];
        int lp = atomicAdd(&cur[bk], 1);
        if (lp < CAP)                           // defensive (P~0 overflow)
            ebuf[bk * CAP + lp] = pk[i];
    }
}

// k_bktfill: per-bucket CSR build, single global pass — the bucket's edges are
// cached in LDS (<=32KB) during the degree-hist pass, then the scatter reads
// from LDS. 1024 threads/block.
__global__ void k_bktfill(const int* __restrict__ ebuf, const int* __restrict__ gcur,
                          const float* __restrict__ x,
                          int* __restrict__ rowptr, int* __restrict__ deg,
                          float* __restrict__ dis, uint2* __restrict__ xs4,
                          int* __restrict__ elist) {
    __shared__ int eb_l[CAP];
    __shared__ int cnt_l[BKT_NODES];
    __shared__ int cur_l[BKT_NODES];
    __shared__ int ps[BKT_NODES];
    int b = blockIdx.x, tid = threadIdx.x;   // 0..1023
    int n0 = b * BKT_NODES;
    int e0 = b * CAP;
    int cnt = min(gcur[b], CAP);
    if (tid < BKT_NODES) cnt_l[tid] = 0;
    __syncthreads();
    for (int i = tid; i < cnt; i += 1024) {
        int pe = ebuf[e0 + i];
        eb_l[i] = pe;
        atomicAdd(&cnt_l[pe & (BKT_NODES - 1)], 1);
    }
    __syncthreads();
    if (tid < BKT_NODES) ps[tid] = cnt_l[tid];
    __syncthreads();
    for (int off = 1; off < BKT_NODES; off <<= 1) {
        int t = 0;
        if (tid < BKT_NODES && tid >= off) t = ps[tid - off];
        __syncthreads();
        if (tid < BKT_NODES) ps[tid] += t;
        __syncthreads();
    }
    if (tid < BKT_NODES) {
        int node = n0 + tid;
        int excl = ps[tid] - cnt_l[tid];       // exclusive scan
        cur_l[tid] = excl;
        if (node < N_NODES) {
            rowptr[node] = e0 + excl;
            deg[node] = cnt_l[tid];
            float dv = rsqrtf((float)cnt_l[tid] + 1.0f);
            dis[node] = dv;
            float x0 = x[node * 3 + 0], x1 = x[node * 3 + 1], x2 = x[node * 3 + 2];
            xs4[node] = make_uint2((unsigned)f2bf(x0 * dv) |
                                   ((unsigned)f2bf(x1 * dv) << 16),
                                   (unsigned)f2bf(x2 * dv));
        }
    }
    __syncthreads();
    for (int i = tid; i < cnt; i += 1024) {
        int pe = eb_l[i];
        int pos = atomicAdd(&cur_l[pe & (BKT_NODES - 1)], 1);
        elist[e0 + pos] = ((unsigned)pe) >> BKT_SHIFT;
    }
}

// ---------------------------------------------------------------------------
// fused layer-1: wave per node. Lane-parallel 3-channel gather over edges
// (predicated, deg<=64 -> usually 1 step), butterfly-reduce, then
// h1 row = relu(aggx@W1 + b1)*dis quantized to uint8[64] + f32 row-scale.
__global__ void k_l1fused(const int* __restrict__ rp, const int* __restrict__ degA,
                          const int* __restrict__ elist,
                          const float* __restrict__ dis, const uint2* __restrict__ xs4,
                          const float* __restrict__ W1, const float* __restrict__ b1,
                          unsigned* __restrict__ h1q32, float* __restrict__ hscale) {
    int node = blockIdx.x * 4 + (threadIdx.x >> 6);
    int lane = threadIdx.x & 63;
    if (node >= N_NODES) return;
    int start = rp[node], dg = degA[node];
    float a0 = 0.f, a1 = 0.f, a2 = 0.f;
    for (int k = 0; k < dg; k += 64) {
        int idx = k + lane;
        bool act = idx < dg;
        int s = elist[start + (act ? idx : 0)];
        uint2 u = xs4[s];
        float msk = act ? 1.0f : 0.0f;
        a0 = fmaf(__uint_as_float(u.x << 16), msk, a0);
        a1 = fmaf(__uint_as_float(u.x & 0xFFFF0000u), msk, a1);
        a2 = fmaf(__uint_as_float(u.y << 16), msk, a2);
    }
#pragma unroll
    for (int off = 1; off < 64; off <<= 1) {
        a0 += __shfl_xor(a0, off);
        a1 += __shfl_xor(a1, off);
        a2 += __shfl_xor(a2, off);
    }
    uint2 un = xs4[node];
    float dn = dis[node];
    a0 = dn * (a0 + __uint_as_float(un.x << 16));
    a1 = dn * (a1 + __uint_as_float(un.x & 0xFFFF0000u));
    a2 = dn * (a2 + __uint_as_float(un.y << 16));
    float v = a0 * W1[lane] + a1 * W1[HIDDEN + lane] + a2 * W1[2 * HIDDEN + lane] + b1[lane];
    v = fmaxf(v, 0.0f) * dn;
    float m = v;
#pragma unroll
    for (int off = 1; off < 64; off <<= 1) m = fmaxf(m, __shfl_xor(m, off));
    float inv = (m > 0.0f) ? 255.0f / m : 0.0f;
    int q = (int)(v * inv + 0.5f);        // 0..255
    int base = lane & ~3;
    unsigned packed = (unsigned)__shfl(q, base) |
                      ((unsigned)__shfl(q, base + 1) << 8) |
                      ((unsigned)__shfl(q, base + 2) << 16) |
                      ((unsigned)__shfl(q, base + 3) << 24);
    unsigned mine = __shfl(packed, lane * 4);   // lanes 0..15 get dwords 0..15
    if (lane < 16) h1q32[node * 16 + lane] = mine;
    if (lane == 0) hscale[node] = m * (1.0f / 255.0f);
}

// ---------------------------------------------------------------------------
// fused 64-channel gather + mean-pool accumulate. Wave per node; 8 edges in
// flight (eg=lane>>3), uint2 row loads, predicated tail. Block's 4 waves
// stage rows in LDS, 64 threads merge same-graph rows, then flush to one of
// NREP gsum replicas (blockIdx&7) -> 8x less atomic contention per word.
__global__ void k_gatherpool(const int* __restrict__ rp, const int* __restrict__ degA,
                             const int* __restrict__ elist,
                             const float* __restrict__ dis,
                             const unsigned char* __restrict__ Hq,
                             const float* __restrict__ Hs,
                             const int* __restrict__ batch,
                             float* __restrict__ gsum8) {
    __shared__ float acc_s[4][HIDDEN];
    __shared__ int gid[4];
    int w = threadIdx.x >> 6, lane = threadIdx.x & 63;
    int node = blockIdx.x * 4 + w;              // 25000*4 = 100000 exact
    int start = rp[node], dg = degA[node];
    int eg = lane >> 3;      // which of 8 concurrent edges
    int ch = lane & 7;       // which byte-octet (uint2) of the row
    float acc[8] = {0.f, 0.f, 0.f, 0.f, 0.f, 0.f, 0.f, 0.f};
    for (int k = 0; k < dg; k += 8) {
        int idx = k + eg;
        bool act = idx < dg;
        int s = elist[start + (act ? idx : 0)];
        float sc = act ? Hs[s] : 0.0f;
        uint2 u = *(const uint2*)(Hq + ((size_t)s << 6) + (ch << 3));
#pragma unroll
        for (int i = 0; i < 4; i++)
            acc[i] = fmaf((float)((u.x >> (8 * i)) & 0xFF), sc, acc[i]);
#pragma unroll
        for (int i = 0; i < 4; i++)
            acc[4 + i] = fmaf((float)((u.y >> (8 * i)) & 0xFF), sc, acc[4 + i]);
    }
#pragma unroll
    for (int i = 0; i < 8; i++) {
        acc[i] += __shfl_xor(acc[i], 8);
        acc[i] += __shfl_xor(acc[i], 16);
        acc[i] += __shfl_xor(acc[i], 32);
    }
    if (lane == 0) gid[w] = batch[node];
    if (lane < 8) {                       // eg==0 lanes hold octet `lane`
        float dn = dis[node];
        float scN = Hs[node];
        uint2 u = *(const uint2*)(Hq + ((size_t)node << 6) + (lane << 3));
        float o[8];
#pragma unroll
        for (int i = 0; i < 4; i++)
            o[i] = dn * fmaf((float)((u.x >> (8 * i)) & 0xFF), scN, acc[i]);
#pragma unroll
        for (int i = 0; i < 4; i++)
            o[4 + i] = dn * fmaf((float)((u.y >> (8 * i)) & 0xFF), scN, acc[4 + i]);
        *(float4*)&acc_s[w][lane * 8]     = make_float4(o[0], o[1], o[2], o[3]);
        *(float4*)&acc_s[w][lane * 8 + 4] = make_float4(o[4], o[5], o[6], o[7]);
    }
    __syncthreads();
    float* gs = gsum8 + (size_t)(blockIdx.x & (NREP - 1)) * (N_GRAPHS * HIDDEN);
    if (threadIdx.x < HIDDEN) {
        int t = threadIdx.x;
#pragma unroll
        for (int wv = 0; wv < 4; wv++) {
            int gw = gid[wv];
            bool first = true;
#pragma unroll
            for (int u = 0; u < wv; u++)
                if (gid[u] == gw) first = false;
            if (first) {
                float s = acc_s[wv][t];
#pragma unroll
                for (int u2 = wv + 1; u2 < 4; u2++)
                    if (gid[u2] == gw) s += acc_s[u2][t];
                atomicAdd(&gs[gw * HIDDEN + t], s);
            }
        }
    }
}

// head: one block (64 thr) per graph; sum the NREP gsum replicas, then
// out[g,c] = (gl @ Wc[:,c]) / max(cnt,1) + bc[c]
__global__ void k_head(const float* __restrict__ gsum8, const int* __restrict__ gstart,
                       const float* __restrict__ Wc, const float* __restrict__ bc,
                       float* __restrict__ out) {
    __shared__ float gl[HIDDEN];
    int g = blockIdx.x, t = threadIdx.x;
    float s = 0.0f;
#pragma unroll
    for (int r = 0; r < NREP; r++)
        s += gsum8[(size_t)r * (N_GRAPHS * HIDDEN) + g * HIDDEN + t];
    gl[t] = s;
    __syncthreads();
    if (t < N_CLASSES) {
        float cntf = fmaxf((float)(gstart[g + 1] - gstart[g]), 1.0f);
        float dot = 0.0f;
#pragma unroll
        for (int k = 0; k < HIDDEN; k++)
            dot = fmaf(gl[k], Wc[k * N_CLASSES + t], dot);
        out[g * N_CLASSES + t] = dot / cntf + bc[t];
    }
}

// ---------------------------------------------------------------------------
extern "C" void kernel_launch(void* const* d_in, const int* in_sizes, int n_in,
                              void* d_out, int out_size, void* d_ws, size_t ws_size,
                              hipStream_t stream) {
    const float* x     = (const float*)d_in[0];
    const int*   ei    = (const int*)  d_in[1];   // [2, N_EDGES] flat: src then dst
    const int*   batch = (const int*)  d_in[2];
    const float* W1    = (const float*)d_in[3];
    const float* b1    = (const float*)d_in[4];
    const float* W2    = (const float*)d_in[5];
    const float* b2    = (const float*)d_in[6];
    const float* Wl    = (const float*)d_in[7];
    const float* bl    = (const float*)d_in[8];
    float* out = (float*)d_out;

    const int* src = ei;
    const int* dst = ei + N_EDGES;

    // workspace layout (4B words; gcur+gsum8 adjacent so ONE memset zeros both;
    // word-offset parity keeps xs4 8B- and h1q 16B-aligned)
    int*   gcur    = (int*)d_ws;                         // 196, pad to 256
    float* gsum8   = (float*)(gcur + 256);               // NREP*512*64
    int*   ebuf    = (int*)(gsum8 + NREP * N_GRAPHS * HIDDEN); // N_BKT*CAP
    int*   elist   = ebuf + N_BKT * CAP;                 // N_BKT*CAP
    int*   rp      = elist + N_BKT * CAP;                // N
    int*   deg     = rp + N_NODES;                       // N
    float* dis     = (float*)(deg + N_NODES);            // N
    float* hscale  = dis + N_NODES;                      // N
    uint2* xs4     = (uint2*)(hscale + N_NODES);         // N uint2 (8B-aligned)
    unsigned* h1q32 = (unsigned*)(xs4 + N_NODES);        // 16N words (uint8 rows)
    int*   gstart  = (int*)(h1q32 + (size_t)N_NODES * 16); // N_GRAPHS+1 (pad 516)
    float* Wc      = (float*)(gstart + 516);             // 64*5
    float* bc      = Wc + HIDDEN * N_CLASSES;            // 5

    const int BS = 256;
    const int g_nodes_sct = (N_NODES + SCT - 1) / SCT;   // 196 gstart blocks
    const int g_wave4 = (N_NODES + 3) / 4;               // wave-per-node kernels

    // zero gcur + all gsum replicas in one memset, then merged scatter kernel
    hipMemsetAsync(gcur, 0, (256 + NREP * N_GRAPHS * HIDDEN) * sizeof(int), stream);
    k_scat<<<EBLK + 1 + g_nodes_sct, SCT, 0, stream>>>(src, dst, W2, Wl, b2, bl, batch,
                                                       gcur, ebuf, Wc, bc, gstart);
    k_bktfill<<<N_BKT, 1024, 0, stream>>>(ebuf, gcur, x, rp, deg, dis, xs4, elist);

    // fused layer 1 (lane-parallel 3ch gather + W1 + quantize to uint8 rows)
    k_l1fused<<<g_wave4, BS, 0, stream>>>(rp, deg, elist, dis, xs4, W1, b1,
                                          h1q32, hscale);

    // layer 2 aggregation fused with mean-pool accumulation (wave per node)
    k_gatherpool<<<N_NODES / 4, BS, 0, stream>>>(rp, deg, elist, dis,
                                                 (const unsigned char*)h1q32,
                                                 hscale, batch, gsum8);

    // folded head (block per graph; sums the NREP replicas)
    k_head<<<N_GRAPHS, HIDDEN, 0, stream>>>(gsum8, gstart, Wc, bc, out);
}

// Round 16
// 162.724 us; speedup vs baseline: 1.3626x; 1.1915x over previous
//
#include <hip/hip_runtime.h>
#include <hip/hip_bf16.h>

#define N_NODES   100000
#define N_EDGES   1250000
#define N_GRAPHS  512
#define HIDDEN    64
#define F_IN      3
#define N_CLASSES 5

// bucket sort parameters
#define BKT_SHIFT 9
#define BKT_NODES 512                                      // nodes per bucket
#define N_BKT     ((N_NODES + BKT_NODES - 1) / BKT_NODES)  // 196
#define CAP       8192                                     // fixed bucket capacity (mean 6400, +22 sigma)
#define EBLK      512                                      // edge blocks in k_scat
#define ECHUNK    ((N_EDGES + EBLK - 1) / EBLK)            // 2442
#define SCT       512                                      // k_scat threads
#define NREP      8                                        // gsum replicas (spread atomic contention)

// bf16 helpers (RNE; inputs are finite)
__device__ __forceinline__ unsigned short f2bf(float f) {
    unsigned u = __float_as_uint(f);
    u += 0x7FFF + ((u >> 16) & 1);
    return (unsigned short)(u >> 16);
}

// ---------------------------------------------------------------------------
// k_scat: merged hist + bucket-base claim + scatter (+ head fold, gstart in
// extra blocks). Edges are cached in LDS during the hist pass, so src/dst are
// read from global exactly once.
__global__ void k_scat(const int* __restrict__ src, const int* __restrict__ dst,
                       const float* __restrict__ W2, const float* __restrict__ Wl,
                       const float* __restrict__ b2, const float* __restrict__ bl,
                       const int* __restrict__ batch,
                       int* __restrict__ gcur, int* __restrict__ ebuf,
                       float* __restrict__ Wc, float* __restrict__ bc,
                       int* __restrict__ gstart) {
    int b = blockIdx.x;
    int tid = threadIdx.x;
    if (b >= EBLK) {
        int bb = b - EBLK;
        if (bb == 0) {                      // head fold: Wc = W2@Wl, bc = b2@Wl+bl
            for (int t = tid; t < HIDDEN * N_CLASSES + N_CLASSES; t += SCT) {
                if (t < HIDDEN * N_CLASSES) {
                    int k = t / N_CLASSES, c = t % N_CLASSES;
                    float acc = 0.0f;
#pragma unroll
                    for (int j = 0; j < HIDDEN; j++)
                        acc = fmaf(W2[k * HIDDEN + j], Wl[j * N_CLASSES + c], acc);
                    Wc[t] = acc;
                } else {
                    int c = t - HIDDEN * N_CLASSES;
                    float acc = bl[c];
#pragma unroll
                    for (int j = 0; j < HIDDEN; j++)
                        acc = fmaf(b2[j], Wl[j * N_CLASSES + c], acc);
                    bc[c] = acc;
                }
            }
            return;
        }
        int n = (bb - 1) * SCT + tid;       // gstart from sorted batch
        if (n >= N_NODES) return;
        if (n == 0) {
            for (int g = 0; g <= batch[0]; g++) gstart[g] = 0;
        } else {
            int b0 = batch[n - 1], b1 = batch[n];
            for (int g = b0 + 1; g <= b1; g++) gstart[g] = n;
        }
        if (n == N_NODES - 1) {
            for (int g = batch[n] + 1; g <= N_GRAPHS; g++) gstart[g] = N_NODES;
        }
        return;
    }
    // scatter blocks: edges cached in LDS across the two passes
    __shared__ int pk[ECHUNK];
    __shared__ unsigned char bkl[ECHUNK];
    __shared__ int h[N_BKT];
    __shared__ int cur[N_BKT];
    for (int i = tid; i < N_BKT; i += SCT) h[i] = 0;
    __syncthreads();
    int e0 = b * ECHUNK;
    int m = min(ECHUNK, N_EDGES - e0);
    for (int i = tid; i < m; i += SCT) {
        int s = src[e0 + i], d = dst[e0 + i];
        int bk = d >> BKT_SHIFT;
        pk[i] = (s << BKT_SHIFT) | (d & (BKT_NODES - 1));
        bkl[i] = (unsigned char)bk;
        atomicAdd(&h[bk], 1);
    }
    __syncthreads();
    for (int i = tid; i < N_BKT; i += SCT)
        cur[i] = atomicAdd(&gcur[i], h[i]);    // claim this block's run in bucket i
    __syncthreads();
    for (int i = tid; i < m; i += SCT) {
        int bk = bkl[i];
        int lp = atomicAdd(&cur[bk], 1);
        if (lp < CAP)                           // defensive (P~0 overflow)
            ebuf[bk * CAP + lp] = pk[i];
    }
}

// k_bktfill: per-bucket CSR build, single global pass — the bucket's edges are
// cached in LDS (<=32KB) during the degree-hist pass, then the scatter reads
// from LDS. 1024 threads/block.
__global__ void k_bktfill(const int* __restrict__ ebuf, const int* __restrict__ gcur,
                          const float* __restrict__ x,
                          int* __restrict__ rowptr, int* __restrict__ deg,
                          float* __restrict__ dis, uint2* __restrict__ xs4,
                          int* __restrict__ elist) {
    __shared__ int eb_l[CAP];
    __shared__ int cnt_l[BKT_NODES];
    __shared__ int cur_l[BKT_NODES];
    __shared__ int ps[BKT_NODES];
    int b = blockIdx.x, tid = threadIdx.x;   // 0..1023
    int n0 = b * BKT_NODES;
    int e0 = b * CAP;
    int cnt = min(gcur[b], CAP);
    if (tid < BKT_NODES) cnt_l[tid] = 0;
    __syncthreads();
    for (int i = tid; i < cnt; i += 1024) {
        int pe = ebuf[e0 + i];
        eb_l[i] = pe;
        atomicAdd(&cnt_l[pe & (BKT_NODES - 1)], 1);
    }
    __syncthreads();
    if (tid < BKT_NODES) ps[tid] = cnt_l[tid];
    __syncthreads();
    for (int off = 1; off < BKT_NODES; off <<= 1) {
        int t = 0;
        if (tid < BKT_NODES && tid >= off) t = ps[tid - off];
        __syncthreads();
        if (tid < BKT_NODES) ps[tid] += t;
        __syncthreads();
    }
    if (tid < BKT_NODES) {
        int node = n0 + tid;
        int excl = ps[tid] - cnt_l[tid];       // exclusive scan
        cur_l[tid] = excl;
        if (node < N_NODES) {
            rowptr[node] = e0 + excl;
            deg[node] = cnt_l[tid];
            float dv = rsqrtf((float)cnt_l[tid] + 1.0f);
            dis[node] = dv;
            float x0 = x[node * 3 + 0], x1 = x[node * 3 + 1], x2 = x[node * 3 + 2];
            xs4[node] = make_uint2((unsigned)f2bf(x0 * dv) |
                                   ((unsigned)f2bf(x1 * dv) << 16),
                                   (unsigned)f2bf(x2 * dv));
        }
    }
    __syncthreads();
    for (int i = tid; i < cnt; i += 1024) {
        int pe = eb_l[i];
        int pos = atomicAdd(&cur_l[pe & (BKT_NODES - 1)], 1);
        elist[e0 + pos] = ((unsigned)pe) >> BKT_SHIFT;
    }
}

// ---------------------------------------------------------------------------
// fused layer-1: FOUR nodes per wave (16 lanes each — matched to mean deg
// 12.5). Lane-parallel 3-channel gather (predicated, usually 1 step), 4-stage
// quarter-butterfly, then each lane computes 4 channels of relu(aggx@W1+b1)*dis,
// local rowmax (4-stage) + LOCAL byte-pack -> coalesced 1-dword/lane store.
__global__ void k_l1fused(const int* __restrict__ rp, const int* __restrict__ degA,
                          const int* __restrict__ elist,
                          const float* __restrict__ dis, const uint2* __restrict__ xs4,
                          const float* __restrict__ W1, const float* __restrict__ b1,
                          unsigned* __restrict__ h1q32, float* __restrict__ hscale) {
    int w = threadIdx.x >> 6, lane = threadIdx.x & 63;
    int q4 = lane >> 4;                   // which of 4 nodes in this wave
    int j  = lane & 15;                   // lane within node (16-wide)
    int node = blockIdx.x * 16 + w * 4 + q4;   // 6250*16 = 100000 exact
    int start = rp[node], dg = degA[node];
    float a0 = 0.f, a1 = 0.f, a2 = 0.f;
    for (int k = 0; k < dg; k += 16) {    // divergent bound across quarters: ok
        int idx = k + j;
        bool act = idx < dg;
        int s = elist[start + (act ? idx : 0)];
        uint2 u = xs4[s];
        float msk = act ? 1.0f : 0.0f;
        a0 = fmaf(__uint_as_float(u.x << 16), msk, a0);
        a1 = fmaf(__uint_as_float(u.x & 0xFFFF0000u), msk, a1);
        a2 = fmaf(__uint_as_float(u.y << 16), msk, a2);
    }
#pragma unroll
    for (int off = 1; off < 16; off <<= 1) {   // butterfly within 16-lane quarter
        a0 += __shfl_xor(a0, off);
        a1 += __shfl_xor(a1, off);
        a2 += __shfl_xor(a2, off);
    }
    uint2 un = xs4[node];
    float dn = dis[node];
    a0 = dn * (a0 + __uint_as_float(un.x << 16));
    a1 = dn * (a1 + __uint_as_float(un.x & 0xFFFF0000u));
    a2 = dn * (a2 + __uint_as_float(un.y << 16));
    // each lane: channels 4j .. 4j+3
    float v[4];
#pragma unroll
    for (int i = 0; i < 4; i++) {
        int c = 4 * j + i;
        float t = a0 * W1[c] + a1 * W1[HIDDEN + c] + a2 * W1[2 * HIDDEN + c] + b1[c];
        v[i] = fmaxf(t, 0.0f) * dn;
    }
    float m = fmaxf(fmaxf(v[0], v[1]), fmaxf(v[2], v[3]));
#pragma unroll
    for (int off = 1; off < 16; off <<= 1) m = fmaxf(m, __shfl_xor(m, off));
    float inv = (m > 0.0f) ? 255.0f / m : 0.0f;
    unsigned packed = 0;
#pragma unroll
    for (int i = 0; i < 4; i++) {
        unsigned qv = (unsigned)(int)(v[i] * inv + 0.5f);   // 0..255
        packed |= qv << (8 * i);
    }
    h1q32[node * 16 + j] = packed;        // 16 consecutive lanes -> 64B row
    if (j == 0) hscale[node] = m * (1.0f / 255.0f);
}

// ---------------------------------------------------------------------------
// fused 64-channel gather + mean-pool accumulate. TWO nodes per wave (32 lanes
// each: 4 edges in flight x 8 uint2-octets). Reduction: 2 xor stages per 2
// nodes (8 bpermutes/node, was 24). Block's 4 waves stage 8 node-rows in LDS,
// 64 threads merge same-graph rows, flush to one of NREP gsum replicas.
__global__ void k_gatherpool(const int* __restrict__ rp, const int* __restrict__ degA,
                             const int* __restrict__ elist,
                             const float* __restrict__ dis,
                             const unsigned char* __restrict__ Hq,
                             const float* __restrict__ Hs,
                             const int* __restrict__ batch,
                             float* __restrict__ gsum8) {
    __shared__ float acc_s[8][HIDDEN];
    __shared__ int gid[8];
    int w = threadIdx.x >> 6, lane = threadIdx.x & 63;
    int half = lane >> 5;                       // which of 2 nodes in this wave
    int l32 = lane & 31;
    int node = blockIdx.x * 8 + w * 2 + half;   // 12500*8 = 100000 exact
    int start = rp[node], dg = degA[node];
    int eg = l32 >> 3;       // which of 4 concurrent edges
    int ch = lane & 7;       // which byte-octet (uint2) of the row
    float acc[8] = {0.f, 0.f, 0.f, 0.f, 0.f, 0.f, 0.f, 0.f};
    for (int k = 0; k < dg; k += 4) {     // divergent bound across halves: ok
        int idx = k + eg;
        bool act = idx < dg;
        int s = elist[start + (act ? idx : 0)];
        float sc = act ? Hs[s] : 0.0f;
        uint2 u = *(const uint2*)(Hq + ((size_t)s << 6) + (ch << 3));
#pragma unroll
        for (int i = 0; i < 4; i++)
            acc[i] = fmaf((float)((u.x >> (8 * i)) & 0xFF), sc, acc[i]);
#pragma unroll
        for (int i = 0; i < 4; i++)
            acc[4 + i] = fmaf((float)((u.y >> (8 * i)) & 0xFF), sc, acc[4 + i]);
    }
#pragma unroll
    for (int i = 0; i < 8; i++) {         // reduce 4 edge-groups (within half)
        acc[i] += __shfl_xor(acc[i], 8);
        acc[i] += __shfl_xor(acc[i], 16);
    }
    if (l32 == 0) gid[w * 2 + half] = batch[node];
    if (l32 < 8) {                        // eg==0 lanes hold octet l32
        float dn = dis[node];
        float scN = Hs[node];
        uint2 u = *(const uint2*)(Hq + ((size_t)node << 6) + (l32 << 3));
        float o[8];
#pragma unroll
        for (int i = 0; i < 4; i++)
            o[i] = dn * fmaf((float)((u.x >> (8 * i)) & 0xFF), scN, acc[i]);
#pragma unroll
        for (int i = 0; i < 4; i++)
            o[4 + i] = dn * fmaf((float)((u.y >> (8 * i)) & 0xFF), scN, acc[4 + i]);
        float* dst = &acc_s[w * 2 + half][l32 * 8];
        *(float4*)(dst)     = make_float4(o[0], o[1], o[2], o[3]);
        *(float4*)(dst + 4) = make_float4(o[4], o[5], o[6], o[7]);
    }
    __syncthreads();
    float* gs = gsum8 + (size_t)(blockIdx.x & (NREP - 1)) * (N_GRAPHS * HIDDEN);
    if (threadIdx.x < HIDDEN) {
        int t = threadIdx.x;
#pragma unroll
        for (int wv = 0; wv < 8; wv++) {
            int gw = gid[wv];
            bool first = true;
#pragma unroll
            for (int u = 0; u < wv; u++)
                if (gid[u] == gw) first = false;
            if (first) {
                float s = acc_s[wv][t];
#pragma unroll
                for (int u2 = wv + 1; u2 < 8; u2++)
                    if (gid[u2] == gw) s += acc_s[u2][t];
                atomicAdd(&gs[gw * HIDDEN + t], s);
            }
        }
    }
}

// head: one block (64 thr) per graph; sum the NREP gsum replicas, then
// out[g,c] = (gl @ Wc[:,c]) / max(cnt,1) + bc[c]
__global__ void k_head(const float* __restrict__ gsum8, const int* __restrict__ gstart,
                       const float* __restrict__ Wc, const float* __restrict__ bc,
                       float* __restrict__ out) {
    __shared__ float gl[HIDDEN];
    int g = blockIdx.x, t = threadIdx.x;
    float s = 0.0f;
#pragma unroll
    for (int r = 0; r < NREP; r++)
        s += gsum8[(size_t)r * (N_GRAPHS * HIDDEN) + g * HIDDEN + t];
    gl[t] = s;
    __syncthreads();
    if (t < N_CLASSES) {
        float cntf = fmaxf((float)(gstart[g + 1] - gstart[g]), 1.0f);
        float dot = 0.0f;
#pragma unroll
        for (int k = 0; k < HIDDEN; k++)
            dot = fmaf(gl[k], Wc[k * N_CLASSES + t], dot);
        out[g * N_CLASSES + t] = dot / cntf + bc[t];
    }
}

// ---------------------------------------------------------------------------
extern "C" void kernel_launch(void* const* d_in, const int* in_sizes, int n_in,
                              void* d_out, int out_size, void* d_ws, size_t ws_size,
                              hipStream_t stream) {
    const float* x     = (const float*)d_in[0];
    const int*   ei    = (const int*)  d_in[1];   // [2, N_EDGES] flat: src then dst
    const int*   batch = (const int*)  d_in[2];
    const float* W1    = (const float*)d_in[3];
    const float* b1    = (const float*)d_in[4];
    const float* W2    = (const float*)d_in[5];
    const float* b2    = (const float*)d_in[6];
    const float* Wl    = (const float*)d_in[7];
    const float* bl    = (const float*)d_in[8];
    float* out = (float*)d_out;

    const int* src = ei;
    const int* dst = ei + N_EDGES;

    // workspace layout (4B words; gcur+gsum8 adjacent so ONE memset zeros both;
    // word-offset parity keeps xs4 8B-aligned)
    int*   gcur    = (int*)d_ws;                         // 196, pad to 256
    float* gsum8   = (float*)(gcur + 256);               // NREP*512*64
    int*   ebuf    = (int*)(gsum8 + NREP * N_GRAPHS * HIDDEN); // N_BKT*CAP
    int*   elist   = ebuf + N_BKT * CAP;                 // N_BKT*CAP
    int*   rp      = elist + N_BKT * CAP;                // N
    int*   deg     = rp + N_NODES;                       // N
    float* dis     = (float*)(deg + N_NODES);            // N
    float* hscale  = dis + N_NODES;                      // N
    uint2* xs4     = (uint2*)(hscale + N_NODES);         // N uint2 (8B-aligned)
    unsigned* h1q32 = (unsigned*)(xs4 + N_NODES);        // 16N words (uint8 rows)
    int*   gstart  = (int*)(h1q32 + (size_t)N_NODES * 16); // N_GRAPHS+1 (pad 516)
    float* Wc      = (float*)(gstart + 516);             // 64*5
    float* bc      = Wc + HIDDEN * N_CLASSES;            // 5

    const int BS = 256;
    const int g_nodes_sct = (N_NODES + SCT - 1) / SCT;   // 196 gstart blocks

    // zero gcur + all gsum replicas in one memset, then merged scatter kernel
    hipMemsetAsync(gcur, 0, (256 + NREP * N_GRAPHS * HIDDEN) * sizeof(int), stream);
    k_scat<<<EBLK + 1 + g_nodes_sct, SCT, 0, stream>>>(src, dst, W2, Wl, b2, bl, batch,
                                                       gcur, ebuf, Wc, bc, gstart);
    k_bktfill<<<N_BKT, 1024, 0, stream>>>(ebuf, gcur, x, rp, deg, dis, xs4, elist);

    // fused layer 1 (4 nodes/wave: 16-lane gather + W1 + local-pack quantize)
    k_l1fused<<<N_NODES / 16, BS, 0, stream>>>(rp, deg, elist, dis, xs4, W1, b1,
                                               h1q32, hscale);

    // layer 2 aggregation fused with mean-pool accumulation (2 nodes/wave)
    k_gatherpool<<<N_NODES / 8, BS, 0, stream>>>(rp, deg, elist, dis,
                                                 (const unsigned char*)h1q32,
                                                 hscale, batch, gsum8);

    // folded head (block per graph; sums the NREP replicas)
    k_head<<<N_GRAPHS, HIDDEN, 0, stream>>>(gsum8, gstart, Wc, bc, out);
}

// Round 17
// 161.570 us; speedup vs baseline: 1.3723x; 1.0071x over previous
//
#include <hip/hip_runtime.h>
#include <hip/hip_bf16.h>

#define N_NODES   100000
#define N_EDGES   1250000
#define N_GRAPHS  512
#define HIDDEN    64
#define F_IN      3
#define N_CLASSES 5

// bucket sort parameters (R17: halved buckets -> 2x bktfill parallelism)
#define BKT_SHIFT 8
#define BKT_NODES 256                                      // nodes per bucket
#define N_BKT     ((N_NODES + BKT_NODES - 1) / BKT_NODES)  // 391
#define CAP       4096                                     // fixed bucket capacity (mean 3200, +15 sigma)
#define EBLK      512                                      // edge blocks in k_scat
#define ECHUNK    ((N_EDGES + EBLK - 1) / EBLK)            // 2442
#define SCT       512                                      // k_scat threads
#define NREP      8                                        // gsum replicas (spread atomic contention)

// bf16 helpers (RNE; inputs are finite)
__device__ __forceinline__ unsigned short f2bf(float f) {
    unsigned u = __float_as_uint(f);
    u += 0x7FFF + ((u >> 16) & 1);
    return (unsigned short)(u >> 16);
}

// ---------------------------------------------------------------------------
// k_scat: merged hist + bucket-base claim + scatter (+ head fold, gstart in
// extra blocks). Edges are cached in LDS during the hist pass, so src/dst are
// read from global exactly once.
__global__ void k_scat(const int* __restrict__ src, const int* __restrict__ dst,
                       const float* __restrict__ W2, const float* __restrict__ Wl,
                       const float* __restrict__ b2, const float* __restrict__ bl,
                       const int* __restrict__ batch,
                       int* __restrict__ gcur, int* __restrict__ ebuf,
                       float* __restrict__ Wc, float* __restrict__ bc,
                       int* __restrict__ gstart) {
    int b = blockIdx.x;
    int tid = threadIdx.x;
    if (b >= EBLK) {
        int bb = b - EBLK;
        if (bb == 0) {                      // head fold: Wc = W2@Wl, bc = b2@Wl+bl
            for (int t = tid; t < HIDDEN * N_CLASSES + N_CLASSES; t += SCT) {
                if (t < HIDDEN * N_CLASSES) {
                    int k = t / N_CLASSES, c = t % N_CLASSES;
                    float acc = 0.0f;
#pragma unroll
                    for (int j = 0; j < HIDDEN; j++)
                        acc = fmaf(W2[k * HIDDEN + j], Wl[j * N_CLASSES + c], acc);
                    Wc[t] = acc;
                } else {
                    int c = t - HIDDEN * N_CLASSES;
                    float acc = bl[c];
#pragma unroll
                    for (int j = 0; j < HIDDEN; j++)
                        acc = fmaf(b2[j], Wl[j * N_CLASSES + c], acc);
                    bc[c] = acc;
                }
            }
            return;
        }
        int n = (bb - 1) * SCT + tid;       // gstart from sorted batch
        if (n >= N_NODES) return;
        if (n == 0) {
            for (int g = 0; g <= batch[0]; g++) gstart[g] = 0;
        } else {
            int b0 = batch[n - 1], b1 = batch[n];
            for (int g = b0 + 1; g <= b1; g++) gstart[g] = n;
        }
        if (n == N_NODES - 1) {
            for (int g = batch[n] + 1; g <= N_GRAPHS; g++) gstart[g] = N_NODES;
        }
        return;
    }
    // scatter blocks: edges cached in LDS across the two passes
    __shared__ int pk[ECHUNK];
    __shared__ unsigned short bkl[ECHUNK];
    __shared__ int h[N_BKT];
    __shared__ int cur[N_BKT];
    for (int i = tid; i < N_BKT; i += SCT) h[i] = 0;
    __syncthreads();
    int e0 = b * ECHUNK;
    int m = min(ECHUNK, N_EDGES - e0);
    for (int i = tid; i < m; i += SCT) {
        int s = src[e0 + i], d = dst[e0 + i];
        int bk = d >> BKT_SHIFT;
        pk[i] = (s << BKT_SHIFT) | (d & (BKT_NODES - 1));
        bkl[i] = (unsigned short)bk;
        atomicAdd(&h[bk], 1);
    }
    __syncthreads();
    for (int i = tid; i < N_BKT; i += SCT)
        cur[i] = atomicAdd(&gcur[i], h[i]);    // claim this block's run in bucket i
    __syncthreads();
    for (int i = tid; i < m; i += SCT) {
        int bk = bkl[i];
        int lp = atomicAdd(&cur[bk], 1);
        if (lp < CAP)                           // defensive (P~0 overflow)
            ebuf[bk * CAP + lp] = pk[i];
    }
}

// k_bktfill: per-bucket CSR build, single global pass — the bucket's edges are
// cached in LDS (<=16KB) during the degree-hist pass, then the scatter reads
// from LDS. 391 blocks x 1024 threads (2 resident blocks/CU).
__global__ void k_bktfill(const int* __restrict__ ebuf, const int* __restrict__ gcur,
                          const float* __restrict__ x,
                          int* __restrict__ rowptr, int* __restrict__ deg,
                          float* __restrict__ dis, uint2* __restrict__ xs4,
                          int* __restrict__ elist) {
    __shared__ int eb_l[CAP];
    __shared__ int cnt_l[BKT_NODES];
    __shared__ int cur_l[BKT_NODES];
    __shared__ int ps[BKT_NODES];
    int b = blockIdx.x, tid = threadIdx.x;   // 0..1023
    int n0 = b * BKT_NODES;
    int e0 = b * CAP;
    int cnt = min(gcur[b], CAP);
    if (tid < BKT_NODES) cnt_l[tid] = 0;
    __syncthreads();
    for (int i = tid; i < cnt; i += 1024) {
        int pe = ebuf[e0 + i];
        eb_l[i] = pe;
        atomicAdd(&cnt_l[pe & (BKT_NODES - 1)], 1);
    }
    __syncthreads();
    if (tid < BKT_NODES) ps[tid] = cnt_l[tid];
    __syncthreads();
    for (int off = 1; off < BKT_NODES; off <<= 1) {
        int t = 0;
        if (tid < BKT_NODES && tid >= off) t = ps[tid - off];
        __syncthreads();
        if (tid < BKT_NODES) ps[tid] += t;
        __syncthreads();
    }
    if (tid < BKT_NODES) {
        int node = n0 + tid;
        int excl = ps[tid] - cnt_l[tid];       // exclusive scan
        cur_l[tid] = excl;
        if (node < N_NODES) {
            rowptr[node] = e0 + excl;
            deg[node] = cnt_l[tid];
            float dv = rsqrtf((float)cnt_l[tid] + 1.0f);
            dis[node] = dv;
            float x0 = x[node * 3 + 0], x1 = x[node * 3 + 1], x2 = x[node * 3 + 2];
            xs4[node] = make_uint2((unsigned)f2bf(x0 * dv) |
                                   ((unsigned)f2bf(x1 * dv) << 16),
                                   (unsigned)f2bf(x2 * dv));
        }
    }
    __syncthreads();
    for (int i = tid; i < cnt; i += 1024) {
        int pe = eb_l[i];
        int pos = atomicAdd(&cur_l[pe & (BKT_NODES - 1)], 1);
        elist[e0 + pos] = ((unsigned)pe) >> BKT_SHIFT;
    }
}

// ---------------------------------------------------------------------------
// fused layer-1: FOUR nodes per wave (16 lanes each — matched to mean deg
// 12.5). Lane-parallel 3-channel gather (predicated, usually 1 step), 4-stage
// quarter-butterfly, then each lane computes 4 channels of relu(aggx@W1+b1)*dis,
// local rowmax (4-stage) + LOCAL byte-pack -> coalesced 1-dword/lane store.
__global__ void k_l1fused(const int* __restrict__ rp, const int* __restrict__ degA,
                          const int* __restrict__ elist,
                          const float* __restrict__ dis, const uint2* __restrict__ xs4,
                          const float* __restrict__ W1, const float* __restrict__ b1,
                          unsigned* __restrict__ h1q32, float* __restrict__ hscale) {
    int w = threadIdx.x >> 6, lane = threadIdx.x & 63;
    int q4 = lane >> 4;                   // which of 4 nodes in this wave
    int j  = lane & 15;                   // lane within node (16-wide)
    int node = blockIdx.x * 16 + w * 4 + q4;   // 6250*16 = 100000 exact
    int start = rp[node], dg = degA[node];
    float a0 = 0.f, a1 = 0.f, a2 = 0.f;
    for (int k = 0; k < dg; k += 16) {    // divergent bound across quarters: ok
        int idx = k + j;
        bool act = idx < dg;
        int s = elist[start + (act ? idx : 0)];
        uint2 u = xs4[s];
        float msk = act ? 1.0f : 0.0f;
        a0 = fmaf(__uint_as_float(u.x << 16), msk, a0);
        a1 = fmaf(__uint_as_float(u.x & 0xFFFF0000u), msk, a1);
        a2 = fmaf(__uint_as_float(u.y << 16), msk, a2);
    }
#pragma unroll
    for (int off = 1; off < 16; off <<= 1) {   // butterfly within 16-lane quarter
        a0 += __shfl_xor(a0, off);
        a1 += __shfl_xor(a1, off);
        a2 += __shfl_xor(a2, off);
    }
    uint2 un = xs4[node];
    float dn = dis[node];
    a0 = dn * (a0 + __uint_as_float(un.x << 16));
    a1 = dn * (a1 + __uint_as_float(un.x & 0xFFFF0000u));
    a2 = dn * (a2 + __uint_as_float(un.y << 16));
    // each lane: channels 4j .. 4j+3
    float v[4];
#pragma unroll
    for (int i = 0; i < 4; i++) {
        int c = 4 * j + i;
        float t = a0 * W1[c] + a1 * W1[HIDDEN + c] + a2 * W1[2 * HIDDEN + c] + b1[c];
        v[i] = fmaxf(t, 0.0f) * dn;
    }
    float m = fmaxf(fmaxf(v[0], v[1]), fmaxf(v[2], v[3]));
#pragma unroll
    for (int off = 1; off < 16; off <<= 1) m = fmaxf(m, __shfl_xor(m, off));
    float inv = (m > 0.0f) ? 255.0f / m : 0.0f;
    unsigned packed = 0;
#pragma unroll
    for (int i = 0; i < 4; i++) {
        unsigned qv = (unsigned)(int)(v[i] * inv + 0.5f);   // 0..255
        packed |= qv << (8 * i);
    }
    h1q32[node * 16 + j] = packed;        // 16 consecutive lanes -> 64B row
    if (j == 0) hscale[node] = m * (1.0f / 255.0f);
}

// ---------------------------------------------------------------------------
// fused 64-channel gather + mean-pool accumulate. TWO nodes per wave (32 lanes
// each: 4 edges in flight x 8 uint2-octets). Reduction: 2 xor stages per 2
// nodes (8 bpermutes/node). Block's 4 waves stage 8 node-rows in LDS,
// 64 threads merge same-graph rows, flush to one of NREP gsum replicas.
__global__ void k_gatherpool(const int* __restrict__ rp, const int* __restrict__ degA,
                             const int* __restrict__ elist,
                             const float* __restrict__ dis,
                             const unsigned char* __restrict__ Hq,
                             const float* __restrict__ Hs,
                             const int* __restrict__ batch,
                             float* __restrict__ gsum8) {
    __shared__ float acc_s[8][HIDDEN];
    __shared__ int gid[8];
    int w = threadIdx.x >> 6, lane = threadIdx.x & 63;
    int half = lane >> 5;                       // which of 2 nodes in this wave
    int l32 = lane & 31;
    int node = blockIdx.x * 8 + w * 2 + half;   // 12500*8 = 100000 exact
    int start = rp[node], dg = degA[node];
    int eg = l32 >> 3;       // which of 4 concurrent edges
    int ch = lane & 7;       // which byte-octet (uint2) of the row
    float acc[8] = {0.f, 0.f, 0.f, 0.f, 0.f, 0.f, 0.f, 0.f};
    for (int k = 0; k < dg; k += 4) {     // divergent bound across halves: ok
        int idx = k + eg;
        bool act = idx < dg;
        int s = elist[start + (act ? idx : 0)];
        float sc = act ? Hs[s] : 0.0f;
        uint2 u = *(const uint2*)(Hq + ((size_t)s << 6) + (ch << 3));
#pragma unroll
        for (int i = 0; i < 4; i++)
            acc[i] = fmaf((float)((u.x >> (8 * i)) & 0xFF), sc, acc[i]);
#pragma unroll
        for (int i = 0; i < 4; i++)
            acc[4 + i] = fmaf((float)((u.y >> (8 * i)) & 0xFF), sc, acc[4 + i]);
    }
#pragma unroll
    for (int i = 0; i < 8; i++) {         // reduce 4 edge-groups (within half)
        acc[i] += __shfl_xor(acc[i], 8);
        acc[i] += __shfl_xor(acc[i], 16);
    }
    if (l32 == 0) gid[w * 2 + half] = batch[node];
    if (l32 < 8) {                        // eg==0 lanes hold octet l32
        float dn = dis[node];
        float scN = Hs[node];
        uint2 u = *(const uint2*)(Hq + ((size_t)node << 6) + (l32 << 3));
        float o[8];
#pragma unroll
        for (int i = 0; i < 4; i++)
            o[i] = dn * fmaf((float)((u.x >> (8 * i)) & 0xFF), scN, acc[i]);
#pragma unroll
        for (int i = 0; i < 4; i++)
            o[4 + i] = dn * fmaf((float)((u.y >> (8 * i)) & 0xFF), scN, acc[4 + i]);
        float* dst = &acc_s[w * 2 + half][l32 * 8];
        *(float4*)(dst)     = make_float4(o[0], o[1], o[2], o[3]);
        *(float4*)(dst + 4) = make_float4(o[4], o[5], o[6], o[7]);
    }
    __syncthreads();
    float* gs = gsum8 + (size_t)(blockIdx.x & (NREP - 1)) * (N_GRAPHS * HIDDEN);
    if (threadIdx.x < HIDDEN) {
        int t = threadIdx.x;
#pragma unroll
        for (int wv = 0; wv < 8; wv++) {
            int gw = gid[wv];
            bool first = true;
#pragma unroll
            for (int u = 0; u < wv; u++)
                if (gid[u] == gw) first = false;
            if (first) {
                float s = acc_s[wv][t];
#pragma unroll
                for (int u2 = wv + 1; u2 < 8; u2++)
                    if (gid[u2] == gw) s += acc_s[u2][t];
                atomicAdd(&gs[gw * HIDDEN + t], s);
            }
        }
    }
}

// head: one block (64 thr) per graph; sum the NREP gsum replicas, then
// out[g,c] = (gl @ Wc[:,c]) / max(cnt,1) + bc[c]
__global__ void k_head(const float* __restrict__ gsum8, const int* __restrict__ gstart,
                       const float* __restrict__ Wc, const float* __restrict__ bc,
                       float* __restrict__ out) {
    __shared__ float gl[HIDDEN];
    int g = blockIdx.x, t = threadIdx.x;
    float s = 0.0f;
#pragma unroll
    for (int r = 0; r < NREP; r++)
        s += gsum8[(size_t)r * (N_GRAPHS * HIDDEN) + g * HIDDEN + t];
    gl[t] = s;
    __syncthreads();
    if (t < N_CLASSES) {
        float cntf = fmaxf((float)(gstart[g + 1] - gstart[g]), 1.0f);
        float dot = 0.0f;
#pragma unroll
        for (int k = 0; k < HIDDEN; k++)
            dot = fmaf(gl[k], Wc[k * N_CLASSES + t], dot);
        out[g * N_CLASSES + t] = dot / cntf + bc[t];
    }
}

// ---------------------------------------------------------------------------
extern "C" void kernel_launch(void* const* d_in, const int* in_sizes, int n_in,
                              void* d_out, int out_size, void* d_ws, size_t ws_size,
                              hipStream_t stream) {
    const float* x     = (const float*)d_in[0];
    const int*   ei    = (const int*)  d_in[1];   // [2, N_EDGES] flat: src then dst
    const int*   batch = (const int*)  d_in[2];
    const float* W1    = (const float*)d_in[3];
    const float* b1    = (const float*)d_in[4];
    const float* W2    = (const float*)d_in[5];
    const float* b2    = (const float*)d_in[6];
    const float* Wl    = (const float*)d_in[7];
    const float* bl    = (const float*)d_in[8];
    float* out = (float*)d_out;

    const int* src = ei;
    const int* dst = ei + N_EDGES;

    // workspace layout (4B words; gcur+gsum8 adjacent so ONE memset zeros both;
    // word-offset parity keeps xs4 8B-aligned)
    int*   gcur    = (int*)d_ws;                         // 391, pad to 512
    float* gsum8   = (float*)(gcur + 512);               // NREP*512*64
    int*   ebuf    = (int*)(gsum8 + NREP * N_GRAPHS * HIDDEN); // N_BKT*CAP
    int*   elist   = ebuf + N_BKT * CAP;                 // N_BKT*CAP
    int*   rp      = elist + N_BKT * CAP;                // N
    int*   deg     = rp + N_NODES;                       // N
    float* dis     = (float*)(deg + N_NODES);            // N
    float* hscale  = dis + N_NODES;                      // N
    uint2* xs4     = (uint2*)(hscale + N_NODES);         // N uint2 (8B-aligned)
    unsigned* h1q32 = (unsigned*)(xs4 + N_NODES);        // 16N words (uint8 rows)
    int*   gstart  = (int*)(h1q32 + (size_t)N_NODES * 16); // N_GRAPHS+1 (pad 516)
    float* Wc      = (float*)(gstart + 516);             // 64*5
    float* bc      = Wc + HIDDEN * N_CLASSES;            // 5

    const int BS = 256;
    const int g_nodes_sct = (N_NODES + SCT - 1) / SCT;   // 196 gstart blocks

    // zero gcur + all gsum replicas in one memset, then merged scatter kernel
    hipMemsetAsync(gcur, 0, (512 + NREP * N_GRAPHS * HIDDEN) * sizeof(int), stream);
    k_scat<<<EBLK + 1 + g_nodes_sct, SCT, 0, stream>>>(src, dst, W2, Wl, b2, bl, batch,
                                                       gcur, ebuf, Wc, bc, gstart);
    k_bktfill<<<N_BKT, 1024, 0, stream>>>(ebuf, gcur, x, rp, deg, dis, xs4, elist);

    // fused layer 1 (4 nodes/wave: 16-lane gather + W1 + local-pack quantize)
    k_l1fused<<<N_NODES / 16, BS, 0, stream>>>(rp, deg, elist, dis, xs4, W1, b1,
                                               h1q32, hscale);

    // layer 2 aggregation fused with mean-pool accumulation (2 nodes/wave)
    k_gatherpool<<<N_NODES / 8, BS, 0, stream>>>(rp, deg, elist, dis,
                                                 (const unsigned char*)h1q32,
                                                 hscale, batch, gsum8);

    // folded head (block per graph; sums the NREP replicas)
    k_head<<<N_GRAPHS, HIDDEN, 0, stream>>>(gsum8, gstart, Wc, bc, out);
}